// Round 1
// baseline (16792.801 us; speedup 1.0000x reference)
//
#include <hip/hip_runtime.h>

// Problem constants
#define TT 512
#define BB 256
#define II 128
#define HH 256
#define CC 10

typedef __attribute__((ext_vector_type(8))) _Float16 f16x8;
typedef __attribute__((ext_vector_type(4))) float    f32x4;

__device__ __forceinline__ float fsig(float x){
  return 1.0f / (1.0f + __expf(-x));
}
__device__ __forceinline__ float ftanh(float x){
  return 2.0f / (1.0f + __expf(-2.0f * x)) - 1.0f;
}

// Persistent recurrent LSTM layer kernel.
//  Grid: 256 WGs x 256 threads. WG (gb = blk&15, gj = blk>>4) owns
//  samples [gb*16, gb*16+16) and hidden units [gj*16, gj*16+16).
//  Wave w (0..3) computes gate w (i,f,g,o) for those 16 units x 16 samples
//  with one 16x16x32 f16 MFMA chain; W fragments live in VGPRs for all T steps.
//  The 16 WGs of a batch-group sync per step via a monotonic atomic counter.
//  blk&15 swizzle puts a group's 16 WGs on one XCD (round-robin heuristic).
template<int KX, bool XF32, bool WRITE_HT>
__global__ __launch_bounds__(256, 2)
void lstm_rec(const float*  __restrict__ xf,      // layer0 input x [B][T][I] fp32
              const _Float16* __restrict__ xh,    // layer1 input h_seq0 [T][B][H] fp16
              const float*  __restrict__ W_hh,    // [4H][H]
              const float*  __restrict__ W_ih,    // [4H][KX]
              const float*  __restrict__ b_ih,
              const float*  __restrict__ b_hh,
              const int*    __restrict__ lengths, // [B]
              _Float16*     __restrict__ h_seq,   // out [T][B][H] fp16
              float*        __restrict__ hT,      // out [B][H] fp32 (last layer)
              unsigned*     __restrict__ ctr)     // [16] per-group counters (zeroed)
{
  constexpr int KXT = KX / 32;
  const int tid  = threadIdx.x;
  const int wv   = tid >> 6;        // wave = gate index
  const int lane = tid & 63;
  const int quad = lane >> 4;
  const int l15  = lane & 15;
  const int blk  = blockIdx.x;
  const int gb   = blk & 15;        // batch group (XCD-local swizzle)
  const int gj   = blk >> 4;        // unit group
  const int b0   = gb << 4;
  const int u0   = gj << 4;
  const int jrow = wv * HH + u0 + l15;   // row of W for this lane's N-column
  const int koff = quad << 3;            // k offset within a 32-wide k-tile

  // Stationary weight fragments (B-operand: B[k][n]=W[j(n)][k], n=lane&15, k=quad*8+e)
  f16x8 wh[8], wx[KXT];
#pragma unroll
  for (int kt = 0; kt < 8; ++kt){
    const float* p = W_hh + (size_t)jrow * HH + kt*32 + koff;
    f16x8 v;
#pragma unroll
    for (int i = 0; i < 8; ++i) v[i] = (_Float16)p[i];
    wh[kt] = v;
  }
#pragma unroll
  for (int kt = 0; kt < KXT; ++kt){
    const float* p = W_ih + (size_t)jrow * KX + kt*32 + koff;
    f16x8 v;
#pragma unroll
    for (int i = 0; i < 8; ++i) v[i] = (_Float16)p[i];
    wx[kt] = v;
  }
  const float bias = b_ih[jrow] + b_hh[jrow];

  // Owner mapping: thread -> one (sample, unit) cell; fp32 state in registers
  const int ob = tid >> 4;
  const int ou = tid & 15;
  const int bg = b0 + ob;
  const int ug = u0 + ou;
  const int len = lengths[bg];
  float c_st = 0.f, h_st = 0.f;

  __shared__ float gex[4][16][17];   // gate exchange, +1 pad
  unsigned* cp = ctr + gb;

  for (int t = 0; t < TT; ++t){
    // Prefetch input-part A fragments (independent of the step barrier)
    f16x8 ax[KXT];
    if constexpr (XF32){
      const float* xp = xf + ((size_t)(b0 + l15) * TT + t) * II + koff;
#pragma unroll
      for (int kt = 0; kt < KXT; ++kt){
        float4 p0 = *(const float4*)(xp + kt*32);
        float4 p1 = *(const float4*)(xp + kt*32 + 4);
        f16x8 a;
        a[0]=(_Float16)p0.x; a[1]=(_Float16)p0.y; a[2]=(_Float16)p0.z; a[3]=(_Float16)p0.w;
        a[4]=(_Float16)p1.x; a[5]=(_Float16)p1.y; a[6]=(_Float16)p1.z; a[7]=(_Float16)p1.w;
        ax[kt] = a;
      }
    } else {
      const _Float16* xp = xh + ((size_t)t * BB + b0 + l15) * HH + koff;
#pragma unroll
      for (int kt = 0; kt < KXT; ++kt){
        ax[kt] = *(const f16x8*)(xp + kt*32);
      }
    }

    // Wait for h[t-1] from all 16 WGs of this batch group
    if (t > 0){
      if (tid == 0){
        while (__hip_atomic_load(cp, __ATOMIC_ACQUIRE, __HIP_MEMORY_SCOPE_AGENT)
               < (unsigned)(t << 4)){
          __builtin_amdgcn_s_sleep(1);
        }
      }
      __syncthreads();
    }

    f32x4 acc = {bias, bias, bias, bias};

    // Recurrent part: h[t-1] @ W_hh^T
    if (t > 0){
      const _Float16* hp = h_seq + ((size_t)(t-1) * BB + b0 + l15) * HH + koff;
#pragma unroll
      for (int kt = 0; kt < 8; ++kt){
        f16x8 a = *(const f16x8*)(hp + kt*32);
        acc = __builtin_amdgcn_mfma_f32_16x16x32_f16(a, wh[kt], acc, 0, 0, 0);
      }
    }
    // Input part: x_t @ W_ih^T
#pragma unroll
    for (int kt = 0; kt < KXT; ++kt){
      acc = __builtin_amdgcn_mfma_f32_16x16x32_f16(ax[kt], wx[kt], acc, 0, 0, 0);
    }

    // D layout: row(b) = quad*4+r, col(unit) = lane&15
#pragma unroll
    for (int r = 0; r < 4; ++r){
      gex[wv][(quad<<2) + r][l15] = acc[r];
    }
    __syncthreads();

    // Elementwise cell update (fp32 state, one cell per thread)
    float iv = fsig (gex[0][ob][ou]);
    float fv = fsig (gex[1][ob][ou]);
    float gv = ftanh(gex[2][ob][ou]);
    float ov = fsig (gex[3][ob][ou]);
    float cn = fv * c_st + iv * gv;
    float hn = ov * ftanh(cn);
    if (t < len){ c_st = cn; h_st = hn; }   // freeze past sequence length
    h_seq[((size_t)t * BB + bg) * HH + ug] = (_Float16)h_st;
    if (WRITE_HT && t == TT-1){
      hT[bg * HH + ug] = h_st;
    }
    __syncthreads();   // all h stores drained (vmcnt) before arrival

    if (tid == 0){
      __threadfence();  // device-scope visibility of this WG's h slice
      __hip_atomic_fetch_add(cp, 1u, __ATOMIC_RELEASE, __HIP_MEMORY_SCOPE_AGENT);
    }
  }
}

// logits = hT @ W_fc^T + b_fc ; softmax over 10 classes. One wave per sample.
__global__ __launch_bounds__(64)
void fc_softmax(const float* __restrict__ hT,
                const float* __restrict__ W_fc,
                const float* __restrict__ b_fc,
                float* __restrict__ out)
{
  const int b = blockIdx.x;
  const int lane = threadIdx.x;
  float p[CC];
#pragma unroll
  for (int c = 0; c < CC; ++c) p[c] = 0.f;
  const float* hb = hT + b * HH;
  for (int k = lane; k < HH; k += 64){
    float hv = hb[k];
#pragma unroll
    for (int c = 0; c < CC; ++c) p[c] += hv * W_fc[c * HH + k];
  }
#pragma unroll
  for (int c = 0; c < CC; ++c){
#pragma unroll
    for (int off = 32; off > 0; off >>= 1) p[c] += __shfl_down(p[c], off);
  }
  if (lane == 0){
    float m = -1e30f;
#pragma unroll
    for (int c = 0; c < CC; ++c){ p[c] += b_fc[c]; m = fmaxf(m, p[c]); }
    float s = 0.f;
#pragma unroll
    for (int c = 0; c < CC; ++c){ p[c] = __expf(p[c] - m); s += p[c]; }
    float inv = 1.0f / s;
#pragma unroll
    for (int c = 0; c < CC; ++c) out[b * CC + c] = p[c] * inv;
  }
}

extern "C" void kernel_launch(void* const* d_in, const int* in_sizes, int n_in,
                              void* d_out, int out_size, void* d_ws, size_t ws_size,
                              hipStream_t stream) {
  const float* x      = (const float*)d_in[0];   // [B][T][I]
  const int*   lens   = (const int*)  d_in[1];   // [B]
  const float* W_fc   = (const float*)d_in[2];   // [C][H]
  const float* b_fc   = (const float*)d_in[3];   // [C]
  const float* W_ih0  = (const float*)d_in[4];   // [4H][I]
  const float* W_hh0  = (const float*)d_in[5];   // [4H][H]
  const float* b_ih0  = (const float*)d_in[6];
  const float* b_hh0  = (const float*)d_in[7];
  const float* W_ih1  = (const float*)d_in[8];   // [4H][H]
  const float* W_hh1  = (const float*)d_in[9];
  const float* b_ih1  = (const float*)d_in[10];
  const float* b_hh1  = (const float*)d_in[11];
  float* out = (float*)d_out;

  char* ws = (char*)d_ws;
  // ws layout: [0,64)   ctr0 (16 u32)
  //            [64,128) ctr1 (16 u32)
  //            [4096, +256KB) hT fp32
  //            then h_seq0, h_seq1 (fp16, 64 MB each)
  unsigned* ctr0 = (unsigned*)(ws);
  unsigned* ctr1 = (unsigned*)(ws + 64);
  float*    hT   = (float*)(ws + 4096);
  _Float16* h0   = (_Float16*)(ws + 4096 + (size_t)BB*HH*sizeof(float));
  _Float16* h1   = h0 + (size_t)TT*BB*HH;

  // zero the barrier counters (ws is re-poisoned before every timed launch)
  hipMemsetAsync(ws, 0, 4096, stream);

  // layer 0: input = x (fp32), KX = I = 128
  lstm_rec<II, true, false><<<dim3(256), dim3(256), 0, stream>>>(
      x, nullptr, W_hh0, W_ih0, b_ih0, b_hh0, lens, h0, nullptr, ctr0);

  // layer 1: input = h_seq0 (fp16), KX = H = 256; writes hT
  lstm_rec<HH, false, true><<<dim3(256), dim3(256), 0, stream>>>(
      nullptr, h0, W_hh1, W_ih1, b_ih1, b_hh1, lens, h1, hT, ctr1);

  fc_softmax<<<dim3(BB), dim3(64), 0, stream>>>(hT, W_fc, b_fc, out);
}

// Round 2
// 2923.775 us; speedup vs baseline: 5.7435x; 5.7435x over previous
//
#include <hip/hip_runtime.h>

// Problem constants
#define TT 512
#define BB 256
#define II 128
#define HH 256
#define CC 10

typedef __attribute__((ext_vector_type(8))) _Float16 f16x8;
typedef __attribute__((ext_vector_type(4))) float    f32x4;

__device__ __forceinline__ float fsig(float x){ return 1.0f/(1.0f+__expf(-x)); }
__device__ __forceinline__ float ftanh(float x){ return 2.0f/(1.0f+__expf(-2.0f*x)) - 1.0f; }

// Poll via relaxed RMW: always executes at the coherence point (IF$), and —
// unlike an acquire load — emits NO buffer_inv (the R1 killer: per-poll L2
// invalidates from 256 WGs thrashed every cache on the chip).
__device__ __forceinline__ unsigned cpoll(unsigned* p){
  return __hip_atomic_fetch_add(p, 0u, __ATOMIC_RELAXED, __HIP_MEMORY_SCOPE_AGENT);
}
__device__ __forceinline__ void spin_until(unsigned* p, unsigned tgt){
  if (threadIdx.x == 0){
    while (cpoll(p) < tgt) __builtin_amdgcn_s_sleep(2);
  }
  asm volatile("" ::: "memory");   // compiler barrier; HW order via issue order
}
// Publish h: write-through past L1+L2 to IF$ (sc0 sc1) — no wbl2/threadfence
// needed. Readers' addresses are first-touch per t, so plain loads are safe.
__device__ __forceinline__ void store_h16(const _Float16* p, _Float16 v){
  unsigned bits = (unsigned)__builtin_bit_cast(unsigned short, v);
  asm volatile("global_store_short %0, %1, off sc0 sc1" :: "v"(p), "v"(bits) : "memory");
}

// One WAVE per WG. Wave owns 16 samples x 16 units, ALL 4 gates:
// 4 independent MFMA chains -> no LDS exchange, no __syncthreads.
// Weights (4 gates x K) stay in VGPRs for all 512 steps.
// 16 WGs per batch-group sync per step via one padded counter (IF$-resident).
template<int KX, bool XF32, bool WRITE_HT>
__device__ __forceinline__ void lstm_layer(
    const float* __restrict__ xf, const _Float16* __restrict__ xh,
    const float* __restrict__ W_hh, const float* __restrict__ W_ih,
    const float* __restrict__ b_ih, const float* __restrict__ b_hh,
    const int* __restrict__ lengths,
    _Float16* __restrict__ h_seq, float* __restrict__ hT,
    unsigned* cown, unsigned* cprod, int gb, int gj)
{
  constexpr int KXT = KX/32;
  const int lane = threadIdx.x & 63;
  const int quad = lane >> 4;
  const int l15  = lane & 15;
  const int koff = quad << 3;      // k = quad*8 + j for A and B fragments
  const int b0 = gb << 4;
  const int u0 = gj << 4;
  const int u  = u0 + l15;         // this lane's unit (B-frag col / D col)

  // Stationary weight fragments: B[k][n] = W[g*H + u][k]
  f16x8 wh[4][8], wx[4][KXT];
  float bias[4];
#pragma unroll
  for (int g = 0; g < 4; ++g){
    const int row = g*HH + u;
#pragma unroll
    for (int kt = 0; kt < 8; ++kt){
      const float* p = W_hh + (size_t)row*HH + kt*32 + koff;
      f16x8 v;
#pragma unroll
      for (int i = 0; i < 8; ++i) v[i] = (_Float16)p[i];
      wh[g][kt] = v;
    }
#pragma unroll
    for (int kt = 0; kt < KXT; ++kt){
      const float* p = W_ih + (size_t)row*KX + kt*32 + koff;
      f16x8 v;
#pragma unroll
      for (int i = 0; i < 8; ++i) v[i] = (_Float16)p[i];
      wx[g][kt] = v;
    }
    bias[g] = b_ih[row] + b_hh[row];
  }

  // D layout: row(sample) = quad*4 + r, col(unit) = l15. Each lane owns 4 cells.
  int sb[4], len[4]; float cst[4], hst[4];
#pragma unroll
  for (int r = 0; r < 4; ++r){
    sb[r]  = b0 + (quad<<2) + r;
    len[r] = lengths[sb[r]];
    cst[r] = 0.f; hst[r] = 0.f;
  }

  for (int t = 0; t < TT; ++t){
    f32x4 acc[4];
#pragma unroll
    for (int g = 0; g < 4; ++g) acc[g] = (f32x4){bias[g],bias[g],bias[g],bias[g]};

    // ---- x-part first: independent of peers' h[t-1] (hides behind the wait)
    f16x8 ax[KXT];
    if constexpr (XF32){
      const float* xp = xf + ((size_t)(b0 + l15)*TT + t)*II + koff;  // A: m=l15
#pragma unroll
      for (int kt = 0; kt < KXT; ++kt){
        float4 p0 = *(const float4*)(xp + kt*32);
        float4 p1 = *(const float4*)(xp + kt*32 + 4);
        f16x8 a;
        a[0]=(_Float16)p0.x; a[1]=(_Float16)p0.y; a[2]=(_Float16)p0.z; a[3]=(_Float16)p0.w;
        a[4]=(_Float16)p1.x; a[5]=(_Float16)p1.y; a[6]=(_Float16)p1.z; a[7]=(_Float16)p1.w;
        ax[kt] = a;
      }
    } else {
      spin_until(cprod, (unsigned)((t+1)<<4));    // producer layer done step t
      const _Float16* xp = xh + ((size_t)t*BB + b0 + l15)*HH + koff;
#pragma unroll
      for (int kt = 0; kt < KXT; ++kt) ax[kt] = *(const f16x8*)(xp + kt*32);
    }
#pragma unroll
    for (int kt = 0; kt < KXT; ++kt)
#pragma unroll
      for (int g = 0; g < 4; ++g)   // 4 independent chains, dep distance 4
        acc[g] = __builtin_amdgcn_mfma_f32_16x16x32_f16(ax[kt], wx[g][kt], acc[g], 0,0,0);

    // ---- recurrent part: wait peers, then h[t-1] @ W_hh^T
    if (t > 0){
      spin_until(cown, (unsigned)(t<<4));
      const _Float16* hp = h_seq + ((size_t)(t-1)*BB + b0 + l15)*HH + koff;
      f16x8 ah[8];
#pragma unroll
      for (int kt = 0; kt < 8; ++kt) ah[kt] = *(const f16x8*)(hp + kt*32);
#pragma unroll
      for (int kt = 0; kt < 8; ++kt)
#pragma unroll
        for (int g = 0; g < 4; ++g)
          acc[g] = __builtin_amdgcn_mfma_f32_16x16x32_f16(ah[kt], wh[g][kt], acc[g], 0,0,0);
    }

    // ---- elementwise cell update: all 4 gates already in this lane's regs
#pragma unroll
    for (int r = 0; r < 4; ++r){
      float iv = fsig (acc[0][r]);
      float fv = fsig (acc[1][r]);
      float gv = ftanh(acc[2][r]);
      float ov = fsig (acc[3][r]);
      float cn = fv*cst[r] + iv*gv;
      float hn = ov*ftanh(cn);
      if (t < len[r]){ cst[r] = cn; hst[r] = hn; }     // freeze past length
      store_h16(&h_seq[((size_t)t*BB + sb[r])*HH + u], (_Float16)hst[r]);
      if (WRITE_HT){ if (t == TT-1) hT[(size_t)sb[r]*HH + u] = hst[r]; }
    }

    // ---- arrive: drain own stores to IF$, then relaxed increment (no wbl2)
    __builtin_amdgcn_s_waitcnt(0);
    asm volatile("" ::: "memory");
    if (lane == 0)
      __hip_atomic_fetch_add(cown, 1u, __ATOMIC_RELAXED, __HIP_MEMORY_SCOPE_AGENT);
  }
}

// Both layers in ONE dispatch, layer1 trailing layer0 by 1 step (pipeline).
// 512 single-wave WGs: blk&15 = batch group (-> XCD gb%8 for both layers
// under round-robin; perf heuristic only, correctness is via IF$-scope ops).
__global__ __launch_bounds__(64, 1)
void lstm_fused(const float* __restrict__ x, const int* __restrict__ lens,
                const float* __restrict__ W_ih0, const float* __restrict__ W_hh0,
                const float* __restrict__ b_ih0, const float* __restrict__ b_hh0,
                const float* __restrict__ W_ih1, const float* __restrict__ W_hh1,
                const float* __restrict__ b_ih1, const float* __restrict__ b_hh1,
                _Float16* __restrict__ h0, _Float16* __restrict__ h1,
                float* __restrict__ hT, unsigned* __restrict__ ctr)
{
  const int blk = blockIdx.x;
  const int gb  = blk & 15;
  const int gj  = (blk >> 4) & 15;
  unsigned* c0 = ctr + gb*32;          // 128B-padded counters (one line each)
  unsigned* c1 = ctr + (16 + gb)*32;
  if (blk < 256){
    lstm_layer<II, true,  false>(x, nullptr, W_hh0, W_ih0, b_ih0, b_hh0, lens,
                                 h0, nullptr, c0, nullptr, gb, gj);
  } else {
    lstm_layer<HH, false, true >(nullptr, h0, W_hh1, W_ih1, b_ih1, b_hh1, lens,
                                 h1, hT, c1, c0, gb, gj);
  }
}

// logits = hT @ W_fc^T + b_fc ; softmax over 10 classes. One wave per sample.
__global__ __launch_bounds__(64)
void fc_softmax(const float* __restrict__ hT,
                const float* __restrict__ W_fc,
                const float* __restrict__ b_fc,
                float* __restrict__ out)
{
  const int b = blockIdx.x;
  const int lane = threadIdx.x;
  float p[CC];
#pragma unroll
  for (int c = 0; c < CC; ++c) p[c] = 0.f;
  const float* hb = hT + b * HH;
  for (int k = lane; k < HH; k += 64){
    float hv = hb[k];
#pragma unroll
    for (int c = 0; c < CC; ++c) p[c] += hv * W_fc[c * HH + k];
  }
#pragma unroll
  for (int c = 0; c < CC; ++c){
#pragma unroll
    for (int off = 32; off > 0; off >>= 1) p[c] += __shfl_down(p[c], off);
  }
  if (lane == 0){
    float m = -1e30f;
#pragma unroll
    for (int c = 0; c < CC; ++c){ p[c] += b_fc[c]; m = fmaxf(m, p[c]); }
    float s = 0.f;
#pragma unroll
    for (int c = 0; c < CC; ++c){ p[c] = __expf(p[c] - m); s += p[c]; }
    float inv = 1.0f / s;
#pragma unroll
    for (int c = 0; c < CC; ++c) out[b * CC + c] = p[c] * inv;
  }
}

extern "C" void kernel_launch(void* const* d_in, const int* in_sizes, int n_in,
                              void* d_out, int out_size, void* d_ws, size_t ws_size,
                              hipStream_t stream) {
  const float* x      = (const float*)d_in[0];   // [B][T][I]
  const int*   lens   = (const int*)  d_in[1];   // [B]
  const float* W_fc   = (const float*)d_in[2];   // [C][H]
  const float* b_fc   = (const float*)d_in[3];   // [C]
  const float* W_ih0  = (const float*)d_in[4];   // [4H][I]
  const float* W_hh0  = (const float*)d_in[5];   // [4H][H]
  const float* b_ih0  = (const float*)d_in[6];
  const float* b_hh0  = (const float*)d_in[7];
  const float* W_ih1  = (const float*)d_in[8];   // [4H][H]
  const float* W_hh1  = (const float*)d_in[9];
  const float* b_ih1  = (const float*)d_in[10];
  const float* b_hh1  = (const float*)d_in[11];
  float* out = (float*)d_out;

  char* ws = (char*)d_ws;
  // ws layout: [0, 8K)      counters (2 layers x 16 groups x 128B)
  //            [8K, +256K)  hT fp32
  //            then h_seq0, h_seq1 (fp16, ~67 MB each)
  unsigned* ctr = (unsigned*)ws;
  float*    hT  = (float*)(ws + 8192);
  _Float16* h0  = (_Float16*)(ws + 8192 + (size_t)BB*HH*sizeof(float));
  _Float16* h1  = h0 + (size_t)TT*BB*HH;

  hipMemsetAsync(ws, 0, 8192, stream);   // zero barrier counters each launch

  lstm_fused<<<dim3(512), dim3(64), 0, stream>>>(
      x, lens, W_ih0, W_hh0, b_ih0, b_hh0, W_ih1, W_hh1, b_ih1, b_hh1,
      h0, h1, hT, ctr);

  fc_softmax<<<dim3(BB), dim3(64), 0, stream>>>(hT, W_fc, b_fc, out);
}

// Round 3
// 1936.976 us; speedup vs baseline: 8.6696x; 1.5095x over previous
//
#include <hip/hip_runtime.h>

// Problem constants
#define TT 512
#define BB 256
#define II 128
#define HH 256
#define CC 10

typedef __attribute__((ext_vector_type(8))) _Float16 f16x8;
typedef __attribute__((ext_vector_type(4))) _Float16 f16x4;
typedef __attribute__((ext_vector_type(4))) float    f32x4;

__device__ __forceinline__ float fsig(float x){ return 1.0f/(1.0f+__expf(-x)); }
__device__ __forceinline__ float ftanh(float x){ return 2.0f/(1.0f+__expf(-2.0f*x)) - 1.0f; }

// Poll via relaxed RMW at the coherence point (no buffer_inv storm — R1 lesson).
__device__ __forceinline__ unsigned cpoll(unsigned* p){
  return __hip_atomic_fetch_add(p, 0u, __ATOMIC_RELAXED, __HIP_MEMORY_SCOPE_AGENT);
}
// Publish h: write-through to IF$ (sc0 sc1). Readers of fresh (first-touch or
// sc-load) addresses are coherent without wbl2/threadfence. (R2-proven.)
__device__ __forceinline__ void store_h16(_Float16* p, _Float16 v){
  unsigned b32 = (unsigned)__builtin_bit_cast(unsigned short, v);
  asm volatile("global_store_short %0, %1, off sc0 sc1" :: "v"(p), "v"(b32) : "memory");
}
// Cache-bypassing 16B load (for the h1 ring, whose addresses are reused every
// 2 steps and may be stale in L1/L2). Caller must waitcnt before use.
__device__ __forceinline__ f16x8 load_sc(const _Float16* p){
  f16x8 r;
  asm volatile("global_load_dwordx4 %0, %1, off sc0 sc1" : "=v"(r) : "v"(p) : "memory");
  return r;
}

// One WG = 256 threads = 4 waves, covering 16 samples x 32 units x all gates.
// Wave w computes gate w for 32 units (2 MFMA N-tiles); its weight fragments
// (fp16, pre-converted) are VGPR-resident for all 512 steps (128 VGPRs max).
// Gate values exchanged intra-WG via LDS; h exchanged across the 8 WGs of a
// batch group via IF$ (sc0sc1 stores + monotonic counter).
template<int KXV, bool IS_L1>
__device__ __forceinline__ void run_layer(
    const _Float16* __restrict__ xin,   // L0: xc [B][T][I] ; L1: h0seq [T][B][H]
    const _Float16* __restrict__ Wh,    // fp16 [4H][H]
    const _Float16* __restrict__ Wx,    // fp16 [4H][KXV]
    const float* __restrict__ b_ih, const float* __restrict__ b_hh,
    const int* __restrict__ lengths,
    _Float16* __restrict__ hout,        // L0: h0seq [T][B][H] ; L1: ring [2][B][H]
    float* __restrict__ hT,
    unsigned* cown, unsigned* cprod, int gb, int gj)
{
  constexpr int KXT = KXV/32;
  const int tid = threadIdx.x;
  const int w   = tid >> 6;        // wave = gate index
  const int lane= tid & 63;
  const int quad= lane >> 4;
  const int l15 = lane & 15;
  const int koff= quad << 3;       // k = quad*8 + j within a 32-wide k-tile
  const int b0  = gb << 4;
  const int u0  = gj << 5;         // 32 units per WG

  // Stationary fp16 weight fragments: direct 16B loads, no per-step remat.
  const int r0 = w*HH + u0 + l15;       // W row for tile0 (units u0+l15)
  const int r1 = r0 + 16;               // tile1 (units u0+16+l15)
  f16x8 wh[2][8], wx[2][KXT];
#pragma unroll
  for(int kt=0;kt<8;++kt){
    wh[0][kt] = *(const f16x8*)(Wh + (size_t)r0*HH + kt*32 + koff);
    wh[1][kt] = *(const f16x8*)(Wh + (size_t)r1*HH + kt*32 + koff);
  }
#pragma unroll
  for(int kt=0;kt<KXT;++kt){
    wx[0][kt] = *(const f16x8*)(Wx + (size_t)r0*KXV + kt*32 + koff);
    wx[1][kt] = *(const f16x8*)(Wx + (size_t)r1*KXV + kt*32 + koff);
  }
  const float bias0 = b_ih[r0] + b_hh[r0];
  const float bias1 = b_ih[r1] + b_hh[r1];

  // Elementwise role: thread owns cells (sample sb, units u0+j and u0+16+j)
  const int s  = tid >> 4;
  const int j  = tid & 15;
  const int sb = b0 + s;
  const int len = lengths[sb];
  float cs0=0.f, hs0=0.f, cs1=0.f, hs1=0.f;

  __shared__ float gex[4][16][33];   // [gate][sample][unit], +1 pad

  // L0: x fragments prefetched one step ahead (x is a constant input)
  f16x8 axn[KXT];
  if(!IS_L1){
    const _Float16* xp = xin + ((size_t)(b0+l15)*TT + 0)*KXV + koff;
#pragma unroll
    for(int kt=0;kt<KXT;++kt) axn[kt] = *(const f16x8*)(xp + kt*32);
  }

  for(int t=0;t<TT;++t){
    f16x8 ax[KXT];
    if(IS_L1){
      // producer (L0 group done step t) + own peers (done step t-1), one poller
      if(tid==0){
        const unsigned tgtp = 8u*(unsigned)(t+1);
        while(cpoll(cprod) < tgtp) __builtin_amdgcn_s_sleep(1);
        if(t>0){ const unsigned tgto = 8u*(unsigned)t;
          while(cpoll(cown) < tgto) __builtin_amdgcn_s_sleep(1); }
      }
      __syncthreads();
      const _Float16* xp = xin + ((size_t)t*BB + b0 + l15)*HH + koff;
#pragma unroll
      for(int kt=0;kt<KXT;++kt) ax[kt] = *(const f16x8*)(xp + kt*32);
    } else {
#pragma unroll
      for(int kt=0;kt<KXT;++kt) ax[kt] = axn[kt];
      if(t>0){
        if(tid==0){ const unsigned tgto = 8u*(unsigned)t;
          while(cpoll(cown) < tgto) __builtin_amdgcn_s_sleep(1); }
        __syncthreads();
      }
    }

    // h[t-1] A-fragments (issued before the x-MFMAs so latency overlaps)
    f16x8 ah[8];
    if(t>0){
      if(IS_L1){
        const _Float16* hp = hout + (((size_t)((t-1)&1))*BB + b0 + l15)*HH + koff;
#pragma unroll
        for(int kt=0;kt<8;++kt) ah[kt] = load_sc(hp + kt*32);
        // tie the loaded regs to the waitcnt so no use can be hoisted above it
        asm volatile("s_waitcnt vmcnt(0)"
          : "+v"(ah[0]),"+v"(ah[1]),"+v"(ah[2]),"+v"(ah[3]),
            "+v"(ah[4]),"+v"(ah[5]),"+v"(ah[6]),"+v"(ah[7]) :: "memory");
      } else {
        const _Float16* hp = hout + ((size_t)(t-1)*BB + b0 + l15)*HH + koff;
#pragma unroll
        for(int kt=0;kt<8;++kt) ah[kt] = *(const f16x8*)(hp + kt*32);
      }
    }

    f32x4 a0 = {bias0,bias0,bias0,bias0};
    f32x4 a1 = {bias1,bias1,bias1,bias1};
#pragma unroll
    for(int kt=0;kt<KXT;++kt){
      a0 = __builtin_amdgcn_mfma_f32_16x16x32_f16(ax[kt], wx[0][kt], a0, 0,0,0);
      a1 = __builtin_amdgcn_mfma_f32_16x16x32_f16(ax[kt], wx[1][kt], a1, 0,0,0);
    }
    if(t>0){
#pragma unroll
      for(int kt=0;kt<8;++kt){
        a0 = __builtin_amdgcn_mfma_f32_16x16x32_f16(ah[kt], wh[0][kt], a0, 0,0,0);
        a1 = __builtin_amdgcn_mfma_f32_16x16x32_f16(ah[kt], wh[1][kt], a1, 0,0,0);
      }
    }

    // D layout: row(sample)=quad*4+rr, col(unit)=l15 (R2-verified)
#pragma unroll
    for(int rr=0;rr<4;++rr){
      gex[w][(quad<<2)+rr][l15]    = a0[rr];
      gex[w][(quad<<2)+rr][16+l15] = a1[rr];
    }
    __syncthreads();

    {
      float iv0 = fsig (gex[0][s][j]);
      float fv0 = fsig (gex[1][s][j]);
      float gv0 = ftanh(gex[2][s][j]);
      float ov0 = fsig (gex[3][s][j]);
      float iv1 = fsig (gex[0][s][16+j]);
      float fv1 = fsig (gex[1][s][16+j]);
      float gv1 = ftanh(gex[2][s][16+j]);
      float ov1 = fsig (gex[3][s][16+j]);
      float cn0 = fv0*cs0 + iv0*gv0;
      float hn0 = ov0*ftanh(cn0);
      float cn1 = fv1*cs1 + iv1*gv1;
      float hn1 = ov1*ftanh(cn1);
      if(t < len){ cs0=cn0; hs0=hn0; cs1=cn1; hs1=hn1; }  // freeze past length
      _Float16* hp = IS_L1
        ? hout + (((size_t)(t&1))*BB + sb)*HH + u0 + j
        : hout + ((size_t)t*BB + sb)*HH + u0 + j;
      store_h16(hp,      (_Float16)hs0);
      store_h16(hp + 16, (_Float16)hs1);
      if(IS_L1 && t==TT-1){
        hT[(size_t)sb*HH + u0 + j]      = hs0;
        hT[(size_t)sb*HH + u0 + 16 + j] = hs1;
      }
    }
    // drain own h stores to IF$ (per wave), align waves, then one arrive/WG
    asm volatile("s_waitcnt vmcnt(0)" ::: "memory");
    __syncthreads();
    if(tid==0)
      __hip_atomic_fetch_add(cown, 1u, __ATOMIC_RELAXED, __HIP_MEMORY_SCOPE_AGENT);

    // prefetch next x AFTER the drain-barrier so the barrier's implicit
    // vmcnt(0) doesn't expose this latency; lands during next poll window
    if(!IS_L1 && t+1 < TT){
      const _Float16* xp = xin + ((size_t)(b0+l15)*TT + (t+1))*KXV + koff;
#pragma unroll
      for(int kt=0;kt<KXT;++kt) axn[kt] = *(const f16x8*)(xp + kt*32);
    }
  }
}

__global__ __launch_bounds__(256, 1)
void lstm_fused(const _Float16* __restrict__ xc,
                const _Float16* __restrict__ Wh0, const _Float16* __restrict__ Wx0,
                const _Float16* __restrict__ Wh1, const _Float16* __restrict__ Wx1,
                const float* __restrict__ b_ih0, const float* __restrict__ b_hh0,
                const float* __restrict__ b_ih1, const float* __restrict__ b_hh1,
                const int* __restrict__ lens,
                _Float16* __restrict__ h0seq, _Float16* __restrict__ h1ring,
                float* __restrict__ hT, unsigned* __restrict__ ctr)
{
  // 256 WGs: layer = blk>>7, gb = blk&15, gj = (blk>>4)&7.
  // blk%8 == gb%8 -> a batch group's 8 WGs AND its partner-layer group share
  // an XCD under round-robin dispatch (L2 locality heuristic only).
  const int blk = blockIdx.x;
  const int layer = blk >> 7;
  const int gb = blk & 15;
  const int gj = (blk >> 4) & 7;
  unsigned* c0 = ctr + gb*32;          // 128B-padded counters
  unsigned* c1 = ctr + (16+gb)*32;
  if(layer==0){
    run_layer<II,false>(xc, Wh0, Wx0, b_ih0, b_hh0, lens, h0seq, nullptr,
                        c0, nullptr, gb, gj);
  } else {
    run_layer<HH,true >(h0seq, Wh1, Wx1, b_ih1, b_hh1, lens, h1ring, hT,
                        c1, c0, gb, gj);
  }
}

// fp32 -> fp16 elementwise convert (vectorized x4)
__global__ __launch_bounds__(256)
void cvt4(const float* __restrict__ in, _Float16* __restrict__ out, int n4)
{
  int i = blockIdx.x*256 + threadIdx.x;
  if(i < n4){
    float4 v = ((const float4*)in)[i];
    f16x4 o;
    o[0]=(_Float16)v.x; o[1]=(_Float16)v.y; o[2]=(_Float16)v.z; o[3]=(_Float16)v.w;
    ((f16x4*)out)[i] = o;
  }
}

// logits = hT @ W_fc^T + b_fc ; softmax over 10 classes. One wave per sample.
__global__ __launch_bounds__(64)
void fc_softmax(const float* __restrict__ hT,
                const float* __restrict__ W_fc,
                const float* __restrict__ b_fc,
                float* __restrict__ out)
{
  const int b = blockIdx.x;
  const int lane = threadIdx.x;
  float p[CC];
#pragma unroll
  for (int c = 0; c < CC; ++c) p[c] = 0.f;
  const float* hb = hT + b * HH;
  for (int k = lane; k < HH; k += 64){
    float hv = hb[k];
#pragma unroll
    for (int c = 0; c < CC; ++c) p[c] += hv * W_fc[c * HH + k];
  }
#pragma unroll
  for (int c = 0; c < CC; ++c){
#pragma unroll
    for (int off = 32; off > 0; off >>= 1) p[c] += __shfl_down(p[c], off);
  }
  if (lane == 0){
    float m = -1e30f;
#pragma unroll
    for (int c = 0; c < CC; ++c){ p[c] += b_fc[c]; m = fmaxf(m, p[c]); }
    float ssum = 0.f;
#pragma unroll
    for (int c = 0; c < CC; ++c){ p[c] = __expf(p[c] - m); ssum += p[c]; }
    float inv = 1.0f / ssum;
#pragma unroll
    for (int c = 0; c < CC; ++c) out[b * CC + c] = p[c] * inv;
  }
}

extern "C" void kernel_launch(void* const* d_in, const int* in_sizes, int n_in,
                              void* d_out, int out_size, void* d_ws, size_t ws_size,
                              hipStream_t stream) {
  const float* x      = (const float*)d_in[0];   // [B][T][I]
  const int*   lens   = (const int*)  d_in[1];   // [B]
  const float* W_fc   = (const float*)d_in[2];   // [C][H]
  const float* b_fc   = (const float*)d_in[3];   // [C]
  const float* W_ih0  = (const float*)d_in[4];   // [4H][I]
  const float* W_hh0  = (const float*)d_in[5];   // [4H][H]
  const float* b_ih0  = (const float*)d_in[6];
  const float* b_hh0  = (const float*)d_in[7];
  const float* W_ih1  = (const float*)d_in[8];   // [4H][H]
  const float* W_hh1  = (const float*)d_in[9];
  const float* b_ih1  = (const float*)d_in[10];
  const float* b_hh1  = (const float*)d_in[11];
  float* out = (float*)d_out;

  char* ws = (char*)d_ws;
  // ws layout (bytes):
  //   [0, 8K)          counters (2 layers x 16 groups x 128B)
  //   [8K, +256K)      hT fp32
  //   [270336 ..)      fp16 weights: Wh0(512K) Wx0(256K) Wh1(512K) Wx1(512K)
  //   [2105344 ..)     xc fp16 [B][T][I]  (32 MB)
  //   [35659776 ..)    h0seq fp16 [T][B][H] (64 MB)
  //   [102768640 ..)   h1 ring fp16 [2][B][H] (256 KB)   total ~103 MB
  unsigned* ctr  = (unsigned*)ws;
  float*    hT   = (float*)(ws + 8192);
  _Float16* Wh0c = (_Float16*)(ws + 270336);
  _Float16* Wx0c = (_Float16*)(ws + 794624);
  _Float16* Wh1c = (_Float16*)(ws + 1056768);
  _Float16* Wx1c = (_Float16*)(ws + 1581056);
  _Float16* xc   = (_Float16*)(ws + 2105344);
  _Float16* h0   = (_Float16*)(ws + 35659776);
  _Float16* h1r  = (_Float16*)(ws + 102768640);

  hipMemsetAsync(ws, 0, 8192, stream);   // zero barrier counters each launch

  // prep: fp32 -> fp16 (weights + x), removes all in-loop conversion work
  cvt4<<<dim3((BB*TT*II/4 + 255)/256), dim3(256), 0, stream>>>(x,     xc,   BB*TT*II/4);
  cvt4<<<dim3((4*HH*HH/4  + 255)/256), dim3(256), 0, stream>>>(W_hh0, Wh0c, 4*HH*HH/4);
  cvt4<<<dim3((4*HH*II/4  + 255)/256), dim3(256), 0, stream>>>(W_ih0, Wx0c, 4*HH*II/4);
  cvt4<<<dim3((4*HH*HH/4  + 255)/256), dim3(256), 0, stream>>>(W_hh1, Wh1c, 4*HH*HH/4);
  cvt4<<<dim3((4*HH*HH/4  + 255)/256), dim3(256), 0, stream>>>(W_ih1, Wx1c, 4*HH*HH/4);

  lstm_fused<<<dim3(256), dim3(256), 0, stream>>>(
      xc, Wh0c, Wx0c, Wh1c, Wx1c, b_ih0, b_hh0, b_ih1, b_hh1, lens,
      h0, h1r, hT, ctr);

  fc_softmax<<<dim3(BB), dim3(64), 0, stream>>>(hT, W_fc, b_fc, out);
}

// Round 4
// 1758.254 us; speedup vs baseline: 9.5508x; 1.1016x over previous
//
#include <hip/hip_runtime.h>

// Problem constants
#define TT 512
#define BB 256
#define II 128
#define HH 256
#define CC 10

typedef __attribute__((ext_vector_type(8))) _Float16 f16x8;
typedef __attribute__((ext_vector_type(4))) _Float16 f16x4;
typedef __attribute__((ext_vector_type(4))) float    f32x4;

__device__ __forceinline__ float fsig(float x){ return 1.0f/(1.0f+__expf(-x)); }
__device__ __forceinline__ float ftanh(float x){ return 2.0f/(1.0f+__expf(-2.0f*x)) - 1.0f; }

// Relaxed RMW poll at the coherence point (no buffer_inv storm — R1 lesson).
__device__ __forceinline__ unsigned cpoll(unsigned* p){
  return __hip_atomic_fetch_add(p, 0u, __ATOMIC_RELAXED, __HIP_MEMORY_SCOPE_AGENT);
}
// Wave-level poll: lane0 spins, result broadcast. No __syncthreads needed.
__device__ __forceinline__ unsigned poll_until(unsigned* p, unsigned tgt){
  unsigned v = 0;
  if((threadIdx.x & 63) == 0){
    v = cpoll(p);
    while(v < tgt){ __builtin_amdgcn_s_sleep(2); v = cpoll(p); }
  }
  unsigned u = __builtin_amdgcn_readfirstlane(v);
  asm volatile("" ::: "memory");   // fence subsequent loads below the poll
  return u;
}
// Publish h: write-through to IF$ (sc0 sc1) — R2/R3-proven visibility.
__device__ __forceinline__ void store_h16(_Float16* p, _Float16 v){
  unsigned b32 = (unsigned)__builtin_bit_cast(unsigned short, v);
  asm volatile("global_store_short %0, %1, off sc0 sc1" :: "v"(p), "v"(b32) : "memory");
}
// L1/L2-bypassing load for ring addresses that are reused across steps.
__device__ __forceinline__ f16x8 load_sc(const _Float16* p){
  f16x8 r;
  asm volatile("global_load_dwordx4 %0, %1, off sc0 sc1" : "=v"(r) : "v"(p) : "memory");
  return r;
}
// Pin a loaded fragment: value becomes asm-defined -> compiler cannot
// rematerialize the load inside the loop (the R2/R3 failure mode).
#define PIN(x) asm volatile("" : "+v"(x))

// One WAVE owns: 16 samples (group gb) x 16 units (gj) x ALL 4 gates.
// 4 independent MFMA chains; all 4 gate values for a cell end up in one lane
// (D: row(sample)=quad*4+r, col(unit)=l15) -> elementwise is wave-local.
// Weights fp16, VGPR-resident (pinned). Cross-wave h exchange via IF$ with
// per-group monotonic counters; wave-level arrive/poll, zero barriers.
template<int KXT, bool IS_L1>
__device__ __forceinline__ void run_wave(
    const _Float16* __restrict__ xin,   // L0: xc [B][T][I] ; L1: h0 [T][B][H]
    const _Float16* __restrict__ Wh,    // fp16 [4H][H]
    const _Float16* __restrict__ Wx,    // fp16 [4H][KXT*32]
    const float* __restrict__ b_ih, const float* __restrict__ b_hh,
    const int* __restrict__ lengths,
    _Float16* __restrict__ hbuf,        // L0: h0 full [T][B][H]; L1: ring [4][B][H]
    float* __restrict__ hT,
    unsigned* cown, unsigned* cprod, int gb, int gj)
{
  constexpr int KXV = KXT*32;
  const int lane = threadIdx.x & 63;
  const int quad = lane >> 4;
  const int l15  = lane & 15;
  const int koff = quad << 3;          // k = quad*8 + j in a 32-wide k-tile
  const int b0   = gb << 4;
  const int u    = (gj << 4) + l15;    // this lane's unit (B col / D col)

  // Stationary weight fragments: B[k][n] = W[g*H+u][k]; pinned in VGPRs.
  f16x8 wh[4][8], wx[4][KXT];
  float bias[4];
#pragma unroll
  for(int g=0; g<4; ++g){
    const int row = g*HH + u;
#pragma unroll
    for(int kt=0; kt<8; ++kt){
      wh[g][kt] = *(const f16x8*)(Wh + (size_t)row*HH + kt*32 + koff);
      PIN(wh[g][kt]);
    }
#pragma unroll
    for(int kt=0; kt<KXT; ++kt){
      wx[g][kt] = *(const f16x8*)(Wx + (size_t)row*KXV + kt*32 + koff);
      PIN(wx[g][kt]);
    }
    bias[g] = b_ih[row] + b_hh[row];
  }

  // Each lane owns 4 cells: samples b0+quad*4+r, unit u. fp32 state in regs.
  int sb[4], len[4]; float cs[4], hs[4];
#pragma unroll
  for(int r=0; r<4; ++r){
    sb[r]  = b0 + (quad<<2) + r;
    len[r] = lengths[sb[r]];
    cs[r] = 0.f; hs[r] = 0.f;
  }

  unsigned lastp = 0, lasto = 0;   // monotone counter caches (skip RMW when ok)

  f16x8 axn[KXT];
  if(!IS_L1){
    const _Float16* xp = xin + ((size_t)(b0+l15)*TT + 0)*KXV + koff;
#pragma unroll
    for(int kt=0; kt<KXT; ++kt) axn[kt] = *(const f16x8*)(xp + kt*32);
  }

  for(int t=0; t<TT; ++t){
    // ---- x-part input fragments
    f16x8 ax[KXT];
    if(IS_L1){
      const unsigned tgtp = 16u*(unsigned)(t+1);          // L0 group done step t
      if(lastp < tgtp) lastp = poll_until(cprod, tgtp);   // usually cached-skip
      const _Float16* xp = xin + ((size_t)t*BB + b0 + l15)*HH + koff;
#pragma unroll
      for(int kt=0; kt<KXT; ++kt) ax[kt] = *(const f16x8*)(xp + kt*32);
    } else {
#pragma unroll
      for(int kt=0; kt<KXT; ++kt) ax[kt] = axn[kt];
    }

    // ---- wait own group peers (h[t-1] complete), then issue h loads
    if(t > 0){
      const unsigned tgto = 16u*(unsigned)t;
      if(lasto < tgto) lasto = poll_until(cown, tgto);
    }
    f16x8 ah[8];
    if(t > 0){
      if(IS_L1){
        const _Float16* hp = hbuf + (((size_t)((t-1)&3))*BB + b0 + l15)*HH + koff;
#pragma unroll
        for(int kt=0; kt<8; ++kt) ah[kt] = load_sc(hp + kt*32);
      } else {
        const _Float16* hp = hbuf + ((size_t)(t-1)*BB + b0 + l15)*HH + koff;
#pragma unroll
        for(int kt=0; kt<8; ++kt) ah[kt] = *(const f16x8*)(hp + kt*32);
      }
    }

    // ---- x-MFMAs run under the h-load latency
    f32x4 acc[4];
#pragma unroll
    for(int g=0; g<4; ++g) acc[g] = (f32x4){bias[g],bias[g],bias[g],bias[g]};
#pragma unroll
    for(int kt=0; kt<KXT; ++kt)
#pragma unroll
      for(int g=0; g<4; ++g)
        acc[g] = __builtin_amdgcn_mfma_f32_16x16x32_f16(ax[kt], wx[g][kt], acc[g], 0,0,0);

    if(t > 0){
      if(IS_L1){
        // asm loads: compiler doesn't know a wait is needed -> tie regs to it
        asm volatile("s_waitcnt vmcnt(0)"
          : "+v"(ah[0]),"+v"(ah[1]),"+v"(ah[2]),"+v"(ah[3]),
            "+v"(ah[4]),"+v"(ah[5]),"+v"(ah[6]),"+v"(ah[7]) :: "memory");
      }
#pragma unroll
      for(int kt=0; kt<8; ++kt)
#pragma unroll
        for(int g=0; g<4; ++g)
          acc[g] = __builtin_amdgcn_mfma_f32_16x16x32_f16(ah[kt], wh[g][kt], acc[g], 0,0,0);
    }

    // ---- elementwise cell update (all gates in-lane, no exchange)
#pragma unroll
    for(int r=0; r<4; ++r){
      float iv = fsig (acc[0][r]);
      float fv = fsig (acc[1][r]);
      float gv = ftanh(acc[2][r]);
      float ov = fsig (acc[3][r]);
      float cn = fv*cs[r] + iv*gv;
      float hn = ov*ftanh(cn);
      if(t < len[r]){ cs[r] = cn; hs[r] = hn; }   // freeze past length
      _Float16* hp = IS_L1
        ? hbuf + (((size_t)(t&3))*BB + sb[r])*HH + u
        : hbuf + ((size_t)t*BB + sb[r])*HH + u;
      store_h16(hp, (_Float16)hs[r]);
      if(IS_L1 && t == TT-1) hT[(size_t)sb[r]*HH + u] = hs[r];
    }

    // ---- drain own stores, arrive (fire-and-forget RMW, off critical path)
    asm volatile("s_waitcnt vmcnt(0)" ::: "memory");
    if(lane == 0)
      __hip_atomic_fetch_add(cown, 1u, __ATOMIC_RELAXED, __HIP_MEMORY_SCOPE_AGENT);

    // ---- prefetch next x AFTER the drain so it isn't waited on; lands
    //      during the next poll window
    if(!IS_L1 && t+1 < TT){
      const _Float16* xp = xin + ((size_t)(b0+l15)*TT + (t+1))*KXV + koff;
#pragma unroll
      for(int kt=0; kt<KXT; ++kt) axn[kt] = *(const f16x8*)(xp + kt*32);
    }
  }
}

// 512 single-wave WGs: layer = blk>>8, gb = blk&15, gj = (blk>>4)&15.
// blk%8 == gb%8 -> a group's 16 waves AND its partner-layer group share an
// XCD under round-robin dispatch (locality heuristic; correctness via IF$).
__global__ __launch_bounds__(64, 1)
void lstm_fused(const _Float16* __restrict__ xc,
                const _Float16* __restrict__ Wh0, const _Float16* __restrict__ Wx0,
                const _Float16* __restrict__ Wh1, const _Float16* __restrict__ Wx1,
                const float* __restrict__ b_ih0, const float* __restrict__ b_hh0,
                const float* __restrict__ b_ih1, const float* __restrict__ b_hh1,
                const int* __restrict__ lens,
                _Float16* __restrict__ h0seq, _Float16* __restrict__ h1ring,
                float* __restrict__ hT, unsigned* __restrict__ ctr)
{
  const int blk   = blockIdx.x;
  const int layer = blk >> 8;
  const int gb    = blk & 15;
  const int gj    = (blk >> 4) & 15;
  unsigned* c0 = ctr + gb*32;          // 128B-padded counters
  unsigned* c1 = ctr + (16+gb)*32;
  if(layer == 0){
    run_wave<4,false>(xc, Wh0, Wx0, b_ih0, b_hh0, lens, h0seq, nullptr,
                      c0, nullptr, gb, gj);
  } else {
    run_wave<8,true >(h0seq, Wh1, Wx1, b_ih1, b_hh1, lens, h1ring, hT,
                      c1, c0, gb, gj);
  }
}

// fp32 -> fp16 elementwise convert (vectorized x4)
__global__ __launch_bounds__(256)
void cvt4(const float* __restrict__ in, _Float16* __restrict__ out, int n4)
{
  int i = blockIdx.x*256 + threadIdx.x;
  if(i < n4){
    float4 v = ((const float4*)in)[i];
    f16x4 o;
    o[0]=(_Float16)v.x; o[1]=(_Float16)v.y; o[2]=(_Float16)v.z; o[3]=(_Float16)v.w;
    ((f16x4*)out)[i] = o;
  }
}

// logits = hT @ W_fc^T + b_fc ; softmax over 10 classes. One wave per sample.
__global__ __launch_bounds__(64)
void fc_softmax(const float* __restrict__ hT,
                const float* __restrict__ W_fc,
                const float* __restrict__ b_fc,
                float* __restrict__ out)
{
  const int b = blockIdx.x;
  const int lane = threadIdx.x;
  float p[CC];
#pragma unroll
  for (int c = 0; c < CC; ++c) p[c] = 0.f;
  const float* hb = hT + b * HH;
  for (int k = lane; k < HH; k += 64){
    float hv = hb[k];
#pragma unroll
    for (int c = 0; c < CC; ++c) p[c] += hv * W_fc[c * HH + k];
  }
#pragma unroll
  for (int c = 0; c < CC; ++c){
#pragma unroll
    for (int off = 32; off > 0; off >>= 1) p[c] += __shfl_down(p[c], off);
  }
  if (lane == 0){
    float m = -1e30f;
#pragma unroll
    for (int c = 0; c < CC; ++c){ p[c] += b_fc[c]; m = fmaxf(m, p[c]); }
    float ssum = 0.f;
#pragma unroll
    for (int c = 0; c < CC; ++c){ p[c] = __expf(p[c] - m); ssum += p[c]; }
    float inv = 1.0f / ssum;
#pragma unroll
    for (int c = 0; c < CC; ++c) out[b * CC + c] = p[c] * inv;
  }
}

extern "C" void kernel_launch(void* const* d_in, const int* in_sizes, int n_in,
                              void* d_out, int out_size, void* d_ws, size_t ws_size,
                              hipStream_t stream) {
  const float* x      = (const float*)d_in[0];   // [B][T][I]
  const int*   lens   = (const int*)  d_in[1];   // [B]
  const float* W_fc   = (const float*)d_in[2];   // [C][H]
  const float* b_fc   = (const float*)d_in[3];   // [C]
  const float* W_ih0  = (const float*)d_in[4];   // [4H][I]
  const float* W_hh0  = (const float*)d_in[5];   // [4H][H]
  const float* b_ih0  = (const float*)d_in[6];
  const float* b_hh0  = (const float*)d_in[7];
  const float* W_ih1  = (const float*)d_in[8];   // [4H][H]
  const float* W_hh1  = (const float*)d_in[9];
  const float* b_ih1  = (const float*)d_in[10];
  const float* b_hh1  = (const float*)d_in[11];
  float* out = (float*)d_out;

  char* ws = (char*)d_ws;
  // ws layout (bytes):
  //   [0, 8K)          counters (2 layers x 16 groups x 128B)
  //   [8K, +256K)      hT fp32
  //   [270336 ..)      fp16 weights: Wh0(512K) Wx0(256K) Wh1(512K) Wx1(512K)
  //   [2105344 ..)     xc fp16 [B][T][I]  (32 MB)
  //   [35659776 ..)    h0seq fp16 [T][B][H] (64 MB)
  //   [102768640 ..)   h1 ring fp16 [4][B][H] (512 KB)   total ~103 MB
  unsigned* ctr  = (unsigned*)ws;
  float*    hT   = (float*)(ws + 8192);
  _Float16* Wh0c = (_Float16*)(ws + 270336);
  _Float16* Wx0c = (_Float16*)(ws + 794624);
  _Float16* Wh1c = (_Float16*)(ws + 1056768);
  _Float16* Wx1c = (_Float16*)(ws + 1581056);
  _Float16* xc   = (_Float16*)(ws + 2105344);
  _Float16* h0   = (_Float16*)(ws + 35659776);
  _Float16* h1r  = (_Float16*)(ws + 102768640);

  hipMemsetAsync(ws, 0, 8192, stream);   // zero barrier counters each launch

  // prep: fp32 -> fp16 (weights + x), removes all in-loop conversion work
  cvt4<<<dim3((BB*TT*II/4 + 255)/256), dim3(256), 0, stream>>>(x,     xc,   BB*TT*II/4);
  cvt4<<<dim3((4*HH*HH/4  + 255)/256), dim3(256), 0, stream>>>(W_hh0, Wh0c, 4*HH*HH/4);
  cvt4<<<dim3((4*HH*II/4  + 255)/256), dim3(256), 0, stream>>>(W_ih0, Wx0c, 4*HH*II/4);
  cvt4<<<dim3((4*HH*HH/4  + 255)/256), dim3(256), 0, stream>>>(W_hh1, Wh1c, 4*HH*HH/4);
  cvt4<<<dim3((4*HH*HH/4  + 255)/256), dim3(256), 0, stream>>>(W_ih1, Wx1c, 4*HH*HH/4);

  lstm_fused<<<dim3(512), dim3(64), 0, stream>>>(
      xc, Wh0c, Wx0c, Wh1c, Wx1c, b_ih0, b_hh0, b_ih1, b_hh1, lens,
      h0, h1r, hT, ctr);

  fc_softmax<<<dim3(BB), dim3(64), 0, stream>>>(hT, W_fc, b_fc, out);
}